// Round 4
// baseline (435.655 us; speedup 1.0000x reference)
//
#include <hip/hip_runtime.h>
#include <hip/hip_bf16.h>

#define NN 100000
#define NE 1600000
#define KF 128     // IN_FEATS
#define CT 256     // NUM_HEADS*OUT_FEATS
#define NH 8

typedef __attribute__((ext_vector_type(8))) short short8;
typedef __attribute__((ext_vector_type(8))) unsigned short ushort8;
typedef __attribute__((ext_vector_type(4))) float f32x4;

__device__ __forceinline__ float bf2f(unsigned short u) {
  union { unsigned int i; float f; } x; x.i = ((unsigned int)u) << 16; return x.f;
}
__device__ __forceinline__ unsigned short f2bf(float f) {
  unsigned int b = __float_as_uint(f);
  b += 0x7fffu + ((b >> 16) & 1u);
  return (unsigned short)(b >> 16);
}

// ---------------- K0: W (128x256 f32) -> Wt (256x128 bf16, transposed) ----------------
__global__ void k_wconv(const float* __restrict__ W, unsigned short* __restrict__ Wt) {
  int i = blockIdx.x * 256 + threadIdx.x;
  if (i < KF * CT) {
    int k = i >> 8, c = i & 255;
    Wt[c * KF + k] = f2bf(W[i]);
  }
}

// ---------------- K1: ft = feat @ W via bf16 MFMA, fused el/er epilogue ----------------
__global__ __launch_bounds__(256) void k_gemm(
    const float* __restrict__ feat, const unsigned short* __restrict__ Wt,
    const float* __restrict__ attn_l, const float* __restrict__ attn_r,
    unsigned short* __restrict__ ftb, float* __restrict__ el, float* __restrict__ er)
{
  __shared__ unsigned short fs[64][136];  // +8 pad: 272B stride -> 2-way alias (free)
  const int tid = threadIdx.x;
  const int lane = tid & 63, w = tid >> 6;
  const int row0 = blockIdx.x * 64;

  for (int i = tid; i < 64 * 32; i += 256) {
    int r = i >> 5, c4 = (i & 31) * 4;
    int gr = row0 + r;
    float4 v = make_float4(0.f, 0.f, 0.f, 0.f);
    if (gr < NN) v = *(const float4*)(feat + (size_t)gr * KF + c4);
    *(ushort4*)(&fs[r][c4]) = make_ushort4(f2bf(v.x), f2bf(v.y), f2bf(v.z), f2bf(v.w));
  }

  const int bc = lane & 15;
  const int bk = (lane >> 4) * 8;
  short8 bfrag[4][4];
#pragma unroll
  for (int ks = 0; ks < 4; ks++)
#pragma unroll
    for (int n = 0; n < 4; n++)
      bfrag[ks][n] = *(const short8*)(Wt + (size_t)(w * 64 + n * 16 + bc) * KF + ks * 32 + bk);

  __syncthreads();

  f32x4 acc[4][4];
#pragma unroll
  for (int m = 0; m < 4; m++)
#pragma unroll
    for (int n = 0; n < 4; n++) acc[m][n] = (f32x4){0.f, 0.f, 0.f, 0.f};

#pragma unroll
  for (int ks = 0; ks < 4; ks++) {
    short8 af[4];
#pragma unroll
    for (int m = 0; m < 4; m++)
      af[m] = *(const short8*)(&fs[m * 16 + bc][ks * 32 + bk]);
#pragma unroll
    for (int m = 0; m < 4; m++)
#pragma unroll
      for (int n = 0; n < 4; n++)
        acc[m][n] = __builtin_amdgcn_mfma_f32_16x16x32_bf16(af[m], bfrag[ks][n], acc[m][n], 0, 0, 0);
  }

  const int rbase = (lane >> 4) * 4;

#pragma unroll
  for (int m = 0; m < 4; m++) {
#pragma unroll
    for (int r = 0; r < 4; r++) {
      int gr = row0 + m * 16 + rbase + r;
      if (gr < NN) {
        unsigned short* op = ftb + (size_t)gr * CT + w * 64 + bc;
#pragma unroll
        for (int n = 0; n < 4; n++) op[n * 16] = f2bf(acc[m][n][r]);
      }
    }
  }

  float al[4], ar[4];
#pragma unroll
  for (int n = 0; n < 4; n++) {
    al[n] = attn_l[w * 64 + n * 16 + bc];
    ar[n] = attn_r[w * 64 + n * 16 + bc];
  }
#pragma unroll
  for (int m = 0; m < 4; m++) {
#pragma unroll
    for (int r = 0; r < 4; r++) {
      float pl0 = acc[m][0][r] * al[0] + acc[m][1][r] * al[1];
      float pl1 = acc[m][2][r] * al[2] + acc[m][3][r] * al[3];
      float pr0 = acc[m][0][r] * ar[0] + acc[m][1][r] * ar[1];
      float pr1 = acc[m][2][r] * ar[2] + acc[m][3][r] * ar[3];
#pragma unroll
      for (int d = 1; d < 16; d <<= 1) {
        pl0 += __shfl_xor(pl0, d);
        pl1 += __shfl_xor(pl1, d);
        pr0 += __shfl_xor(pr0, d);
        pr1 += __shfl_xor(pr1, d);
      }
      if (bc == 0) {
        int gr = row0 + m * 16 + rbase + r;
        if (gr < NN) {
          *(float2*)(el + (size_t)gr * NH + 2 * w) = make_float2(pl0, pl1);
          *(float2*)(er + (size_t)gr * NH + 2 * w) = make_float2(pr0, pr1);
        }
      }
    }
  }
}

// ---------------- K3: in-degree histogram ----------------
__global__ void k_hist(const int* __restrict__ dst, int* __restrict__ cnt) {
  int e = blockIdx.x * 256 + threadIdx.x;
  if (e < NE) atomicAdd(&cnt[dst[e]], 1);
}

// ---------------- K4a: per-block sums ----------------
__global__ __launch_bounds__(1024) void k_scan1(const int* __restrict__ cnt, int* __restrict__ bsum) {
  __shared__ int ws[16];
  const int tid = threadIdx.x, lane = tid & 63, wid = tid >> 6;
  int i = blockIdx.x * 1024 + tid;
  int x = (i < NN) ? cnt[i] : 0;
#pragma unroll
  for (int d = 1; d < 64; d <<= 1) x += __shfl_xor(x, d);
  if (lane == 0) ws[wid] = x;
  __syncthreads();
  if (tid == 0) {
    int s = 0;
#pragma unroll
    for (int k = 0; k < 16; k++) s += ws[k];
    bsum[blockIdx.x] = s;
  }
}

// ---------------- K4b: scan block sums ----------------
__global__ void k_scan2(const int* __restrict__ bsum, int* __restrict__ bexc, int nb) {
  __shared__ int wsum[2];
  const int tid = threadIdx.x, lane = tid & 63, wid = tid >> 6;
  int x = (tid < nb) ? bsum[tid] : 0;
  int v = x;
#pragma unroll
  for (int d = 1; d < 64; d <<= 1) { int t = __shfl_up(v, d); if (lane >= d) v += t; }
  if (lane == 63) wsum[wid] = v;
  __syncthreads();
  int pre = (wid > 0) ? wsum[0] : 0;
  if (tid < nb) bexc[tid] = pre + v - x;
}

// ---------------- K4c: apply offsets ----------------
__global__ __launch_bounds__(1024) void k_scan3(const int* __restrict__ cnt, const int* __restrict__ bexc,
                                                int* __restrict__ off, int* __restrict__ cur) {
  __shared__ int ws[16];
  const int tid = threadIdx.x, lane = tid & 63, wid = tid >> 6;
  int i = blockIdx.x * 1024 + tid;
  int x = (i < NN) ? cnt[i] : 0;
  int v = x;
#pragma unroll
  for (int d = 1; d < 64; d <<= 1) { int t = __shfl_up(v, d); if (lane >= d) v += t; }
  if (lane == 63) ws[wid] = v;
  __syncthreads();
  if (tid < 16) {
    int s = ws[tid];
#pragma unroll
    for (int d = 1; d < 16; d <<= 1) { int t = __shfl_up(s, d); if (tid >= d) s += t; }
    ws[tid] = s;
  }
  __syncthreads();
  int pre = bexc[blockIdx.x] + (wid > 0 ? ws[wid - 1] : 0);
  if (i < NN) { int e = pre + v - x; off[i] = e; cur[i] = e; }
  if (blockIdx.x == 0 && tid == 0) off[NN] = NE;
}

// ---------------- K5: scatter edges into CSR (int2 = {src, eid}) ----------------
__global__ void k_scatter(const int* __restrict__ src, const int* __restrict__ dst,
                          int* __restrict__ cur, int2* __restrict__ csr_se) {
  int e = blockIdx.x * 256 + threadIdx.x;
  if (e < NE) {
    int sv = src[e];
    int d = dst[e];
    int p = atomicAdd(&cur[d], 1);
    csr_se[p] = make_int2(sv, e);
  }
}

// ---------------- K6: per-node softmax + aggregation ----------------
// 1 wave = 1 node. Softmax layout: lane = eg*8 + h (eg = edge-in-group 0..7, h = head).
// Aggregation layout: 32 lanes per row, 16B/lane; half = lane>>5 covers edge parity.
__global__ __launch_bounds__(256) void k_edge(
    const int* __restrict__ off, const int2* __restrict__ csr_se,
    const float* __restrict__ el, const float* __restrict__ er,
    const unsigned short* __restrict__ ftb, const float* __restrict__ bias,
    float* __restrict__ hout, float* __restrict__ attn_out)
{
  const int wid = threadIdx.x >> 6;
  const int lane = threadIdx.x & 63;
  const int n = blockIdx.x * 4 + wid;
  if (n >= NN) return;
  const int beg = off[n], end = off[n + 1];
  if (end == beg) {
    // degree 0: output = bias mean (bias is read anyway below for generality)
    if (lane < 4) {
      float b[8];
#pragma unroll
      for (int k = 0; k < 8; k++) {
        float s = 0.f;
#pragma unroll
        for (int hh = 0; hh < NH; hh++) s += bias[hh * 32 + lane * 8 + k];
        b[k] = s * 0.125f;
      }
      float* op = hout + (size_t)n * 32 + lane * 8;
      *(float4*)(op) = make_float4(b[0], b[1], b[2], b[3]);
      *(float4*)(op + 4) = make_float4(b[4], b[5], b[6], b[7]);
    }
    return;
  }

  const int h = lane & 7;       // head (softmax layout)
  const int eg = lane >> 3;     // edge-in-group (softmax layout)
  const int c8 = lane & 31;     // col-octet (aggregation layout): cols c8*8..c8*8+7
  const int half = lane >> 5;   // edge parity (aggregation layout)
  const int myh = c8 >> 2;      // head of owned cols
  const float er_v = er[(size_t)n * NH + h];

  // pass 1: softmax denominator per head (branchless, loads unconditional)
  float sum = 0.f;
  for (int g = beg; g < end; g += 8) {
    int s = g + eg;
    int sc = (s < end) ? s : (end - 1);
    int sn = csr_se[sc].x;
    float e = el[(size_t)sn * NH + h] + er_v;
    e = (e > 0.f) ? e : 0.2f * e;
    float wv = (s < end) ? __expf(e) : 0.f;
    wv += __shfl_xor(wv, 8); wv += __shfl_xor(wv, 16); wv += __shfl_xor(wv, 32);
    sum += wv;
  }
  const float inv = 1.f / sum;

  // pass 2: attn write + aggregation (16B gathers, 2 rows per step)
  float acc[8];
#pragma unroll
  for (int k = 0; k < 8; k++) acc[k] = 0.f;

  for (int g = beg; g < end; g += 8) {
    int s = g + eg;
    bool valid = (s < end);
    int sc = valid ? s : (end - 1);
    int2 se = csr_se[sc];
    float e = el[(size_t)se.x * NH + h] + er_v;
    e = (e > 0.f) ? e : 0.2f * e;
    float a = valid ? (__expf(e) * inv) : 0.f;
    if (valid) __builtin_nontemporal_store(a, attn_out + (size_t)se.y * NH + h);

#pragma unroll
    for (int t = 0; t < 4; t++) {
      int j = 2 * t + half;
      float aj = __shfl(a, j * 8 + myh);
      int sj = __shfl(se.x, j * 8);
      ushort8 u = *(const ushort8*)(ftb + (size_t)sj * CT + c8 * 8);
#pragma unroll
      for (int k = 0; k < 8; k++) acc[k] += bf2f(u[k]) * aj;
    }
  }

  // fold edge parity, then heads (bits 2..4 of c8)
#pragma unroll
  for (int k = 0; k < 8; k++) acc[k] += __shfl_xor(acc[k], 32);
#pragma unroll
  for (int mks = 4; mks <= 16; mks <<= 1) {
#pragma unroll
    for (int k = 0; k < 8; k++) acc[k] += __shfl_xor(acc[k], mks);
  }

  if (lane < 4) {
    float o[8];
#pragma unroll
    for (int k = 0; k < 8; k++) {
      float b = 0.f;
#pragma unroll
      for (int hh = 0; hh < NH; hh++) b += bias[hh * 32 + lane * 8 + k];
      o[k] = (acc[k] + b) * 0.125f;
    }
    float* op = hout + (size_t)n * 32 + lane * 8;
    __builtin_nontemporal_store(o[0], op + 0);
    __builtin_nontemporal_store(o[1], op + 1);
    __builtin_nontemporal_store(o[2], op + 2);
    __builtin_nontemporal_store(o[3], op + 3);
    __builtin_nontemporal_store(o[4], op + 4);
    __builtin_nontemporal_store(o[5], op + 5);
    __builtin_nontemporal_store(o[6], op + 6);
    __builtin_nontemporal_store(o[7], op + 7);
  }
}

extern "C" void kernel_launch(void* const* d_in, const int* in_sizes, int n_in,
                              void* d_out, int out_size, void* d_ws, size_t ws_size,
                              hipStream_t stream) {
  const float* feat   = (const float*)d_in[0];
  const int*   src    = (const int*)d_in[1];
  const int*   dst    = (const int*)d_in[2];
  const float* W      = (const float*)d_in[3];
  const float* attn_l = (const float*)d_in[4];
  const float* attn_r = (const float*)d_in[5];
  const float* bias   = (const float*)d_in[6];

  char* ws = (char*)d_ws;
  size_t o = 0;
  unsigned short* ftb = (unsigned short*)(ws + o); o += (size_t)NN * CT * 2;  // 51.2 MB
  int2* csr_se        = (int2*)(ws + o);           o += (size_t)NE * 8;       // 12.8 MB
  float* el           = (float*)(ws + o);          o += (size_t)NN * NH * 4;
  float* er           = (float*)(ws + o);          o += (size_t)NN * NH * 4;
  int* cnt            = (int*)(ws + o);            o += (size_t)NN * 4;
  int* off            = (int*)(ws + o);            o += (size_t)(NN + 2) * 4;
  int* cur            = (int*)(ws + o);            o += (size_t)NN * 4;
  unsigned short* Wt  = (unsigned short*)(ws + o); o += (size_t)CT * KF * 2;
  int* bsum           = (int*)(ws + o);            o += 128 * 4;
  int* bexc           = (int*)(ws + o);            o += 128 * 4;

  float* hout     = (float*)d_out;                 // NN*32
  float* attn_out = hout + (size_t)NN * 32;        // NE*8

  const int NB = (NN + 1023) / 1024;  // 98

  k_wconv<<<(KF * CT + 255) / 256, 256, 0, stream>>>(W, Wt);
  k_gemm<<<(NN + 63) / 64, 256, 0, stream>>>(feat, Wt, attn_l, attn_r, ftb, el, er);
  hipMemsetAsync(cnt, 0, NN * sizeof(int), stream);
  k_hist<<<(NE + 255) / 256, 256, 0, stream>>>(dst, cnt);
  k_scan1<<<NB, 1024, 0, stream>>>(cnt, bsum);
  k_scan2<<<1, 128, 0, stream>>>(bsum, bexc, NB);
  k_scan3<<<NB, 1024, 0, stream>>>(cnt, bexc, off, cur);
  k_scatter<<<(NE + 255) / 256, 256, 0, stream>>>(src, dst, cur, csr_se);
  k_edge<<<(NN + 3) / 4, 256, 0, stream>>>(off, csr_se, el, er, ftb, bias, hout, attn_out);
}

// Round 5
// 406.303 us; speedup vs baseline: 1.0722x; 1.0722x over previous
//
#include <hip/hip_runtime.h>
#include <hip/hip_bf16.h>

#define NN 100000
#define NE 1600000
#define KF 128     // IN_FEATS
#define CT 256     // NUM_HEADS*OUT_FEATS
#define NH 8

typedef __attribute__((ext_vector_type(8))) short short8;
typedef __attribute__((ext_vector_type(4))) float f32x4;

__device__ __forceinline__ float bf2f(unsigned short u) {
  union { unsigned int i; float f; } x; x.i = ((unsigned int)u) << 16; return x.f;
}
__device__ __forceinline__ unsigned short f2bf(float f) {
  unsigned int b = __float_as_uint(f);
  b += 0x7fffu + ((b >> 16) & 1u);
  return (unsigned short)(b >> 16);
}

// ---------------- K0: W (128x256 f32) -> Wt (256x128 bf16, transposed) ----------------
__global__ void k_wconv(const float* __restrict__ W, unsigned short* __restrict__ Wt) {
  int i = blockIdx.x * 256 + threadIdx.x;
  if (i < KF * CT) {
    int k = i >> 8, c = i & 255;
    Wt[c * KF + k] = f2bf(W[i]);
  }
}

// ---------------- K1: ft = feat @ W via bf16 MFMA + el/er epilogue + fused hist ----------------
__global__ __launch_bounds__(256) void k_gemm(
    const float* __restrict__ feat, const unsigned short* __restrict__ Wt,
    const float* __restrict__ attn_l, const float* __restrict__ attn_r,
    unsigned short* __restrict__ ftb, float* __restrict__ el, float* __restrict__ er,
    const int* __restrict__ dst, int* __restrict__ cnt)
{
  __shared__ unsigned short fs[64][136];  // +8 pad: 272B stride -> 2-way alias (free)
  const int tid = threadIdx.x;
  const int lane = tid & 63, w = tid >> 6;
  const int row0 = blockIdx.x * 64;

  for (int i = tid; i < 64 * 32; i += 256) {
    int r = i >> 5, c4 = (i & 31) * 4;
    int gr = row0 + r;
    float4 v = make_float4(0.f, 0.f, 0.f, 0.f);
    if (gr < NN) v = *(const float4*)(feat + (size_t)gr * KF + c4);
    *(ushort4*)(&fs[r][c4]) = make_ushort4(f2bf(v.x), f2bf(v.y), f2bf(v.z), f2bf(v.w));
  }

  const int bc = lane & 15;
  const int bk = (lane >> 4) * 8;
  short8 bfrag[4][4];
#pragma unroll
  for (int ks = 0; ks < 4; ks++)
#pragma unroll
    for (int n = 0; n < 4; n++)
      bfrag[ks][n] = *(const short8*)(Wt + (size_t)(w * 64 + n * 16 + bc) * KF + ks * 32 + bk);

  __syncthreads();

  f32x4 acc[4][4];
#pragma unroll
  for (int m = 0; m < 4; m++)
#pragma unroll
    for (int n = 0; n < 4; n++) acc[m][n] = (f32x4){0.f, 0.f, 0.f, 0.f};

#pragma unroll
  for (int ks = 0; ks < 4; ks++) {
    short8 af[4];
#pragma unroll
    for (int m = 0; m < 4; m++)
      af[m] = *(const short8*)(&fs[m * 16 + bc][ks * 32 + bk]);
#pragma unroll
    for (int m = 0; m < 4; m++)
#pragma unroll
      for (int n = 0; n < 4; n++)
        acc[m][n] = __builtin_amdgcn_mfma_f32_16x16x32_bf16(af[m], bfrag[ks][n], acc[m][n], 0, 0, 0);
  }

  const int rbase = (lane >> 4) * 4;

#pragma unroll
  for (int m = 0; m < 4; m++) {
#pragma unroll
    for (int r = 0; r < 4; r++) {
      int gr = row0 + m * 16 + rbase + r;
      if (gr < NN) {
        unsigned short* op = ftb + (size_t)gr * CT + w * 64 + bc;
#pragma unroll
        for (int n = 0; n < 4; n++) op[n * 16] = f2bf(acc[m][n][r]);
      }
    }
  }

  float al[4], ar[4];
#pragma unroll
  for (int n = 0; n < 4; n++) {
    al[n] = attn_l[w * 64 + n * 16 + bc];
    ar[n] = attn_r[w * 64 + n * 16 + bc];
  }
#pragma unroll
  for (int m = 0; m < 4; m++) {
#pragma unroll
    for (int r = 0; r < 4; r++) {
      float pl0 = acc[m][0][r] * al[0] + acc[m][1][r] * al[1];
      float pl1 = acc[m][2][r] * al[2] + acc[m][3][r] * al[3];
      float pr0 = acc[m][0][r] * ar[0] + acc[m][1][r] * ar[1];
      float pr1 = acc[m][2][r] * ar[2] + acc[m][3][r] * ar[3];
#pragma unroll
      for (int d = 1; d < 16; d <<= 1) {
        pl0 += __shfl_xor(pl0, d);
        pl1 += __shfl_xor(pl1, d);
        pr0 += __shfl_xor(pr0, d);
        pr1 += __shfl_xor(pr1, d);
      }
      if (bc == 0) {
        int gr = row0 + m * 16 + rbase + r;
        if (gr < NN) {
          *(float2*)(el + (size_t)gr * NH + 2 * w) = make_float2(pl0, pl1);
          *(float2*)(er + (size_t)gr * NH + 2 * w) = make_float2(pr0, pr1);
        }
      }
    }
  }

  // fused in-degree histogram (independent tail work, overlaps with epilogue drain)
  for (int e = blockIdx.x * 256 + tid; e < NE; e += gridDim.x * 256)
    atomicAdd(&cnt[dst[e]], 1);
}

// ---------------- K4a: per-block sums ----------------
__global__ __launch_bounds__(1024) void k_scan1(const int* __restrict__ cnt, int* __restrict__ bsum) {
  __shared__ int ws[16];
  const int tid = threadIdx.x, lane = tid & 63, wid = tid >> 6;
  int i = blockIdx.x * 1024 + tid;
  int x = (i < NN) ? cnt[i] : 0;
#pragma unroll
  for (int d = 1; d < 64; d <<= 1) x += __shfl_xor(x, d);
  if (lane == 0) ws[wid] = x;
  __syncthreads();
  if (tid == 0) {
    int s = 0;
#pragma unroll
    for (int k = 0; k < 16; k++) s += ws[k];
    bsum[blockIdx.x] = s;
  }
}

// ---------------- K4b: scan block sums ----------------
__global__ void k_scan2(const int* __restrict__ bsum, int* __restrict__ bexc, int nb) {
  __shared__ int wsum[2];
  const int tid = threadIdx.x, lane = tid & 63, wid = tid >> 6;
  int x = (tid < nb) ? bsum[tid] : 0;
  int v = x;
#pragma unroll
  for (int d = 1; d < 64; d <<= 1) { int t = __shfl_up(v, d); if (lane >= d) v += t; }
  if (lane == 63) wsum[wid] = v;
  __syncthreads();
  int pre = (wid > 0) ? wsum[0] : 0;
  if (tid < nb) bexc[tid] = pre + v - x;
}

// ---------------- K4c: apply offsets ----------------
__global__ __launch_bounds__(1024) void k_scan3(const int* __restrict__ cnt, const int* __restrict__ bexc,
                                                int* __restrict__ off, int* __restrict__ cur) {
  __shared__ int ws[16];
  const int tid = threadIdx.x, lane = tid & 63, wid = tid >> 6;
  int i = blockIdx.x * 1024 + tid;
  int x = (i < NN) ? cnt[i] : 0;
  int v = x;
#pragma unroll
  for (int d = 1; d < 64; d <<= 1) { int t = __shfl_up(v, d); if (lane >= d) v += t; }
  if (lane == 63) ws[wid] = v;
  __syncthreads();
  if (tid < 16) {
    int s = ws[tid];
#pragma unroll
    for (int d = 1; d < 16; d <<= 1) { int t = __shfl_up(s, d); if (tid >= d) s += t; }
    ws[tid] = s;
  }
  __syncthreads();
  int pre = bexc[blockIdx.x] + (wid > 0 ? ws[wid - 1] : 0);
  if (i < NN) { int e = pre + v - x; off[i] = e; cur[i] = e; }
  if (blockIdx.x == 0 && tid == 0) off[NN] = NE;
}

// ---------------- K5: scatter edges into CSR (int2 = {src, eid}) ----------------
__global__ void k_scatter(const int* __restrict__ src, const int* __restrict__ dst,
                          int* __restrict__ cur, int2* __restrict__ csr_se) {
  int e = blockIdx.x * 256 + threadIdx.x;
  if (e < NE) {
    int sv = src[e];
    int d = dst[e];
    int p = atomicAdd(&cur[d], 1);
    csr_se[p] = make_int2(sv, e);
  }
}

// ---------------- K6: per-node softmax + aggregation, single fused pass ----------------
// 1 wave = 1 node. Softmax layout: lane = eg*8 + h. Aggregation layout: lane owns cols lane*4..+3.
__global__ __launch_bounds__(256) void k_edge(
    const int* __restrict__ off, const int2* __restrict__ csr_se,
    const float* __restrict__ el, const float* __restrict__ er,
    const unsigned short* __restrict__ ftb, const float* __restrict__ bias,
    float* __restrict__ hout, float* __restrict__ attn_out)
{
  const int wid = threadIdx.x >> 6;
  const int lane = threadIdx.x & 63;
  const int n = blockIdx.x * 4 + wid;
  if (n >= NN) return;
  const int beg = off[n], end = off[n + 1];

  if (end == beg) {  // degree 0: output = summed bias / 8
    if (lane < 8) {
      float b0 = 0.f, b1 = 0.f, b2 = 0.f, b3 = 0.f;
#pragma unroll
      for (int hh = 0; hh < NH; hh++) {
        const float* bp = bias + hh * 32 + lane * 4;
        b0 += bp[0]; b1 += bp[1]; b2 += bp[2]; b3 += bp[3];
      }
      float* op = hout + (size_t)n * 32 + lane * 4;
      *(float4*)op = make_float4(b0 * 0.125f, b1 * 0.125f, b2 * 0.125f, b3 * 0.125f);
    }
    return;
  }

  const int h = lane & 7;       // head (softmax layout)
  const int eg = lane >> 3;     // edge-in-group (softmax layout)
  const int h_own = lane >> 3;  // head owned in aggregation layout
  const float er_v = er[(size_t)n * NH + h];
  const int ng = (end - beg + 7) >> 3;

  float acc0 = 0.f, acc1 = 0.f, acc2 = 0.f, acc3 = 0.f;
  float sum = 0.f;

  if (ng <= 8) {
    // ---- fast path (deg <= 64): single pass, register-cached wv/eid ----
    float ca[8];
    int ceid[8];
#pragma unroll
    for (int g = 0; g < 8; g++) {
      ca[g] = 0.f; ceid[g] = 0;
      if (g < ng) {
        int s = beg + g * 8 + eg;
        bool valid = (s < end);
        int sc = valid ? s : (end - 1);
        int2 se = csr_se[sc];
        float e = el[(size_t)se.x * NH + h] + er_v;
        e = (e > 0.f) ? e : 0.2f * e;
        float wv = valid ? __expf(e) : 0.f;
        ca[g] = wv; ceid[g] = se.y;
        float red = wv;
        red += __shfl_xor(red, 8); red += __shfl_xor(red, 16); red += __shfl_xor(red, 32);
        sum += red;
        // aggregation with UNNORMALIZED weights; scale by inv after the loop
        ushort4 u[8];
        float av[8];
#pragma unroll
        for (int j = 0; j < 8; j++) {
          av[j] = __shfl(wv, j * 8 + h_own);
          int sj = __shfl(se.x, j * 8);
          u[j] = *(const ushort4*)(ftb + (size_t)sj * CT + lane * 4);
        }
#pragma unroll
        for (int j = 0; j < 8; j++) {
          acc0 += bf2f(u[j].x) * av[j];
          acc1 += bf2f(u[j].y) * av[j];
          acc2 += bf2f(u[j].z) * av[j];
          acc3 += bf2f(u[j].w) * av[j];
        }
      }
    }
    const float inv = 1.f / sum;
    const float invh = __shfl(inv, h_own);  // inv of the head this lane's cols belong to
    acc0 *= invh; acc1 *= invh; acc2 *= invh; acc3 *= invh;
    // attn writes from cache
#pragma unroll
    for (int g = 0; g < 8; g++) {
      if (g < ng) {
        int s = beg + g * 8 + eg;
        if (s < end)
          __builtin_nontemporal_store(ca[g] * inv, attn_out + (size_t)ceid[g] * NH + h);
      }
    }
  } else {
    // ---- fallback (deg > 64): two-pass recompute ----
    for (int g = beg; g < end; g += 8) {
      int s = g + eg;
      int sc = (s < end) ? s : (end - 1);
      int sn = csr_se[sc].x;
      float e = el[(size_t)sn * NH + h] + er_v;
      e = (e > 0.f) ? e : 0.2f * e;
      float wv = (s < end) ? __expf(e) : 0.f;
      wv += __shfl_xor(wv, 8); wv += __shfl_xor(wv, 16); wv += __shfl_xor(wv, 32);
      sum += wv;
    }
    const float inv = 1.f / sum;
    for (int g = beg; g < end; g += 8) {
      int s = g + eg;
      bool valid = (s < end);
      int sc = valid ? s : (end - 1);
      int2 se = csr_se[sc];
      float e = el[(size_t)se.x * NH + h] + er_v;
      e = (e > 0.f) ? e : 0.2f * e;
      float a = valid ? (__expf(e) * inv) : 0.f;
      if (valid) __builtin_nontemporal_store(a, attn_out + (size_t)se.y * NH + h);
      ushort4 u[8];
      float av[8];
#pragma unroll
      for (int j = 0; j < 8; j++) {
        av[j] = __shfl(a, j * 8 + h_own);
        int sj = __shfl(se.x, j * 8);
        u[j] = *(const ushort4*)(ftb + (size_t)sj * CT + lane * 4);
      }
#pragma unroll
      for (int j = 0; j < 8; j++) {
        acc0 += bf2f(u[j].x) * av[j];
        acc1 += bf2f(u[j].y) * av[j];
        acc2 += bf2f(u[j].z) * av[j];
        acc3 += bf2f(u[j].w) * av[j];
      }
    }
  }

  // fold heads (lanes differing in bits 3..5 share the same col block)
#pragma unroll
  for (int mks = 8; mks <= 32; mks <<= 1) {
    acc0 += __shfl_xor(acc0, mks);
    acc1 += __shfl_xor(acc1, mks);
    acc2 += __shfl_xor(acc2, mks);
    acc3 += __shfl_xor(acc3, mks);
  }
  if (lane < 8) {
    float b0 = 0.f, b1 = 0.f, b2 = 0.f, b3 = 0.f;
#pragma unroll
    for (int hh = 0; hh < NH; hh++) {
      const float* bp = bias + hh * 32 + lane * 4;
      b0 += bp[0]; b1 += bp[1]; b2 += bp[2]; b3 += bp[3];
    }
    float* op = hout + (size_t)n * 32 + lane * 4;
    __builtin_nontemporal_store((acc0 + b0) * 0.125f, op + 0);
    __builtin_nontemporal_store((acc1 + b1) * 0.125f, op + 1);
    __builtin_nontemporal_store((acc2 + b2) * 0.125f, op + 2);
    __builtin_nontemporal_store((acc3 + b3) * 0.125f, op + 3);
  }
}

extern "C" void kernel_launch(void* const* d_in, const int* in_sizes, int n_in,
                              void* d_out, int out_size, void* d_ws, size_t ws_size,
                              hipStream_t stream) {
  const float* feat   = (const float*)d_in[0];
  const int*   src    = (const int*)d_in[1];
  const int*   dst    = (const int*)d_in[2];
  const float* W      = (const float*)d_in[3];
  const float* attn_l = (const float*)d_in[4];
  const float* attn_r = (const float*)d_in[5];
  const float* bias   = (const float*)d_in[6];

  char* ws = (char*)d_ws;
  size_t o = 0;
  unsigned short* ftb = (unsigned short*)(ws + o); o += (size_t)NN * CT * 2;  // 51.2 MB
  int2* csr_se        = (int2*)(ws + o);           o += (size_t)NE * 8;       // 12.8 MB
  float* el           = (float*)(ws + o);          o += (size_t)NN * NH * 4;
  float* er           = (float*)(ws + o);          o += (size_t)NN * NH * 4;
  int* cnt            = (int*)(ws + o);            o += (size_t)NN * 4;
  int* off            = (int*)(ws + o);            o += (size_t)(NN + 2) * 4;
  int* cur            = (int*)(ws + o);            o += (size_t)NN * 4;
  unsigned short* Wt  = (unsigned short*)(ws + o); o += (size_t)CT * KF * 2;
  int* bsum           = (int*)(ws + o);            o += 128 * 4;
  int* bexc           = (int*)(ws + o);            o += 128 * 4;

  float* hout     = (float*)d_out;                 // NN*32
  float* attn_out = hout + (size_t)NN * 32;        // NE*8

  const int NB = (NN + 1023) / 1024;  // 98
  const int GB = (NN + 63) / 64;      // 1563

  hipMemsetAsync(cnt, 0, NN * sizeof(int), stream);
  k_wconv<<<(KF * CT + 255) / 256, 256, 0, stream>>>(W, Wt);
  k_gemm<<<GB, 256, 0, stream>>>(feat, Wt, attn_l, attn_r, ftb, el, er, dst, cnt);
  k_scan1<<<NB, 1024, 0, stream>>>(cnt, bsum);
  k_scan2<<<1, 128, 0, stream>>>(bsum, bexc, NB);
  k_scan3<<<NB, 1024, 0, stream>>>(cnt, bexc, off, cur);
  k_scatter<<<(NE + 255) / 256, 256, 0, stream>>>(src, dst, cur, csr_se);
  k_edge<<<(NN + 3) / 4, 256, 0, stream>>>(off, csr_se, el, er, ftb, bias, hout, attn_out);
}